// Round 1
// baseline (329.417 us; speedup 1.0000x reference)
//
#include <hip/hip_runtime.h>
#include <hip/hip_bf16.h>

// Problem constants (setup_inputs is fixed: B=4, T=4096, H=1024, T_hist=256)
#define B_ 4
#define T_ 4096
#define H_ 1024
#define WP2 320  // P width: col j <-> token (q&~63) - 256 + j

typedef short  s16x8 __attribute__((ext_vector_type(8)));
typedef float  f32x4 __attribute__((ext_vector_type(4)));
typedef unsigned short u16;

static __device__ __forceinline__ u16 bf16rn(float f) {
  unsigned int u = __float_as_uint(f);
  u += 0x7fffu + ((u >> 16) & 1u);
  return (u16)(u >> 16);
}

// async 16B global -> LDS (direct-to-shared DMA; LDS dest = wave base + lane*16)
static __device__ __forceinline__ void gl2lds16(const u16* g, u16* l) {
  __builtin_amdgcn_global_load_lds(
      (__attribute__((address_space(1))) void*)(g),
      (__attribute__((address_space(3))) void*)(l), 16, 0, 0);
}

// ---------------------------------------------------------------------------
// Kernel 1: h (fp32) -> hb (bf16 row-major) + hbT (bf16, per-batch [H][T])
// ---------------------------------------------------------------------------
__global__ __launch_bounds__(256) void k_convT(const float* __restrict__ h,
                                               u16* __restrict__ hb,
                                               u16* __restrict__ hbT) {
  __shared__ u16 tile[64][72];
  const int b  = blockIdx.z;
  const int t0 = blockIdx.y * 64;
  const int c0 = blockIdx.x * 64;
  const int t  = threadIdx.x;
  {
    const int r  = t >> 2;
    const int cq = (t & 3) << 4;
    const size_t g = (size_t)(b * T_ + t0 + r) * H_ + c0 + cq;
    const f32x4* src = (const f32x4*)(h + g);
    u16 o[16];
#pragma unroll
    for (int v = 0; v < 4; ++v) {
      f32x4 x = src[v];
#pragma unroll
      for (int j = 0; j < 4; ++j) o[v * 4 + j] = bf16rn(x[j]);
    }
    s16x8 w0, w1;
#pragma unroll
    for (int j = 0; j < 8; ++j) { w0[j] = (short)o[j]; w1[j] = (short)o[8 + j]; }
    *(s16x8*)(hb + g)     = w0;
    *(s16x8*)(hb + g + 8) = w1;
    *(s16x8*)&tile[r][cq]     = w0;
    *(s16x8*)&tile[r][cq + 8] = w1;
  }
  __syncthreads();
  {
    const int c  = t >> 2;
    const int ch = t & 3;
#pragma unroll
    for (int p = 0; p < 2; ++p) {
      const int k0 = (ch + p * 4) * 8;
      s16x8 w;
#pragma unroll
      for (int j = 0; j < 8; ++j) w[j] = (short)tile[k0 + j][c];
      *(s16x8*)(hbT + (size_t)(b * H_ + c0 + c) * T_ + t0 + k0) = w;
    }
  }
}

// ---------------------------------------------------------------------------
// Kernel 2: W (fp32) -> Wb (bf16)
// ---------------------------------------------------------------------------
__global__ __launch_bounds__(256) void k_convW(const float* __restrict__ src,
                                               u16* __restrict__ dst) {
  const int i = (blockIdx.x * 256 + threadIdx.x) * 8;
  f32x4 a = *(const f32x4*)(src + i);
  f32x4 b = *(const f32x4*)(src + i + 4);
  s16x8 w;
#pragma unroll
  for (int j = 0; j < 4; ++j) {
    w[j]     = (short)bf16rn(a[j]);
    w[4 + j] = (short)bf16rn(b[j]);
  }
  *(s16x8*)(dst + i) = w;
}

// ---------------------------------------------------------------------------
// Kernel 3: Kb = hb . Wb^T  (M=16384, N=1024, K=1024), m97-style:
// fragment-linear LDS (chunk id = row*4 + quad, 16B each) + global_load_lds.
// XCD-aware bijective swizzle (m204): nwg=1024, each XCD owns 16 contiguous
// row-panels x all 8 col-tiles -> A-panel fetched once per XCD, not 8x.
// ---------------------------------------------------------------------------
__global__ __launch_bounds__(256) void k_gemmK(const u16* __restrict__ hb,
                                               const u16* __restrict__ Wb,
                                               u16* __restrict__ Kb) {
  __shared__ __align__(16) u16 As[512 * 8];   // 128 rows x 4 chunks of 16B
  __shared__ __align__(16) u16 Bs[512 * 8];
  const int t = threadIdx.x;
  const int id  = blockIdx.y * gridDim.x + blockIdx.x;  // 0..1023, x fastest
  const int swz = (id & 7) * 128 + (id >> 3);           // bijective (1024%8==0)
  const int row0 = (swz >> 3) * 128;
  const int col0 = (swz & 7) * 128;
  const int lane = t & 63, wv = t >> 6;
  const int wr = wv >> 1, wc = wv & 1;
  const int l15 = lane & 15, quad = lane >> 4;

  const int c0 = t, c1 = t + 256;
  const size_t gA0 = (size_t)(row0 + (c0 >> 2)) * H_ + (c0 & 3) * 8;
  const size_t gA1 = (size_t)(row0 + (c1 >> 2)) * H_ + (c1 & 3) * 8;
  const size_t gB0 = (size_t)(col0 + (c0 >> 2)) * H_ + (c0 & 3) * 8;
  const size_t gB1 = (size_t)(col0 + (c1 >> 2)) * H_ + (c1 & 3) * 8;

  f32x4 acc[4][4];
#pragma unroll
  for (int m = 0; m < 4; ++m)
#pragma unroll
    for (int n = 0; n < 4; ++n) acc[m][n] = (f32x4)0.0f;

  for (int k0 = 0; k0 < H_; k0 += 32) {
    __syncthreads();
    gl2lds16(hb + gA0 + k0, &As[c0 * 8]);
    gl2lds16(hb + gA1 + k0, &As[c1 * 8]);
    gl2lds16(Wb + gB0 + k0, &Bs[c0 * 8]);
    gl2lds16(Wb + gB1 + k0, &Bs[c1 * 8]);
    __syncthreads();
    s16x8 aF[4], bF[4];
#pragma unroll
    for (int mt = 0; mt < 4; ++mt)
      aF[mt] = *(const s16x8*)&As[((wr * 64 + mt * 16 + l15) * 4 + quad) * 8];
#pragma unroll
    for (int nt = 0; nt < 4; ++nt)
      bF[nt] = *(const s16x8*)&Bs[((wc * 64 + nt * 16 + l15) * 4 + quad) * 8];
#pragma unroll
    for (int mt = 0; mt < 4; ++mt)
#pragma unroll
      for (int nt = 0; nt < 4; ++nt)
        acc[mt][nt] = __builtin_amdgcn_mfma_f32_16x16x32_bf16(aF[mt], bF[nt],
                                                              acc[mt][nt], 0, 0, 0);
  }
#pragma unroll
  for (int mt = 0; mt < 4; ++mt)
#pragma unroll
    for (int nt = 0; nt < 4; ++nt)
#pragma unroll
      for (int r = 0; r < 4; ++r) {
        const int row = row0 + wr * 64 + mt * 16 + quad * 4 + r;
        const int col = col0 + wc * 64 + nt * 16 + l15;
        Kb[(size_t)row * H_ + col] = bf16rn(acc[mt][nt][r]);
      }
}

// ---------------------------------------------------------------------------
// Kernel 4: banded scores + softmax -> P (width 320, block-64-relative cols).
// Block = 32 queries, 512 threads = 8 waves: (qt 0..1) x (sub 0..3).
// NO LDS STAGING (m169 lesson: band is L2-resident). B-fragments are read
// directly from Kb: 4 lanes x 16B = 64B contiguous per token row; zero
// barriers in the K-loop; waves free-run. One __syncthreads for Sred only.
// XCD swizzle keeps each XCD's blocks on a contiguous ~4.5MB K slice.
// ---------------------------------------------------------------------------
__global__ __launch_bounds__(512) void k_scores(const u16* __restrict__ hb,
                                                const u16* __restrict__ Kb,
                                                u16* __restrict__ P) {
  __shared__ float Sred[2][4][16];
  const int t = threadIdx.x;
  const int wv = t >> 6, lane = t & 63;
  const int l15 = lane & 15, quad = lane >> 4;
  const int id  = blockIdx.x;                 // 0..511
  const int swz = (id & 7) * 64 + (id >> 3);  // bijective XCD swizzle
  const int b  = swz >> 7;
  const int q0 = (swz & 127) * 32;
  const int qt = wv & 1;
  const int sub = wv >> 1;
  const int qt0 = q0 + qt * 16;
  const int ktbase = (sub == 0) ? 0 : (1 + sub * 4);   // 0,5,9,13
  const int nkt = (sub == 0) ? 5 : 4;

  const u16* qbase = hb + (size_t)(b * T_ + qt0 + l15) * H_ + quad * 8;

  // per-tile K base pointers; token = q0-256 + (qt+ktbase+i)*16 + l15
  const u16* kbas[5];
#pragma unroll
  for (int i = 0; i < 5; ++i) {
    int tok = q0 - 256 + (qt + ktbase + i) * 16 + l15;
    if (tok < 0) tok = 0;                // garbage rows, masked below
    kbas[i] = Kb + (size_t)(b * T_ + tok) * H_ + quad * 8;
  }

  f32x4 acc[5];
#pragma unroll
  for (int i = 0; i < 5; ++i) acc[i] = (f32x4)0.0f;

#pragma unroll
  for (int hh = 0; hh < H_; hh += 64) {
#pragma unroll
    for (int kk = 0; kk < 2; ++kk) {
      const s16x8 aQ = *(const s16x8*)(qbase + hh + kk * 32);
#pragma unroll
      for (int i = 0; i < 5; ++i) {
        if (i < nkt) {                   // wave-uniform
          const s16x8 bK = *(const s16x8*)(kbas[i] + hh + kk * 32);
          acc[i] = __builtin_amdgcn_mfma_f32_16x16x32_bf16(aQ, bK, acc[i], 0, 0, 0);
        }
      }
    }
  }

  const float scale = 0.03125f;  // 1/sqrt(1024); |scores|<~6 so raw exp is safe
#pragma unroll
  for (int r = 0; r < 4; ++r) {
    const int q = qt0 + quad * 4 + r;
    float sum = 0.0f;
#pragma unroll
    for (int i = 0; i < 5; ++i) {
      if (i < nkt) {
        const int k = qt0 - 256 + (ktbase + i) * 16 + l15;
        const bool valid = (k >= 0) && (k <= q) && (k >= q - 255);
        const float p = valid ? __expf(acc[i][r] * scale) : 0.0f;
        acc[i][r] = p;
        sum += p;
      }
    }
    sum += __shfl_xor(sum, 1);
    sum += __shfl_xor(sum, 2);
    sum += __shfl_xor(sum, 4);
    sum += __shfl_xor(sum, 8);
    if (l15 == 0) Sred[qt][sub][quad * 4 + r] = sum;
  }
  __syncthreads();
  const int toff = ((q0 & 32) >> 4) + qt;  // q-tile slot within 64-block: 0..3
#pragma unroll
  for (int r = 0; r < 4; ++r) {
    const int q = qt0 + quad * 4 + r;
    const int row = quad * 4 + r;
    const float inv = 1.0f / (Sred[qt][0][row] + Sred[qt][1][row] +
                              Sred[qt][2][row] + Sred[qt][3][row]);
    u16* prow = P + (size_t)(b * T_ + q) * WP2;
#pragma unroll
    for (int i = 0; i < 5; ++i)
      if (i < nkt) prow[(toff + ktbase + i) * 16 + l15] = bf16rn(acc[i][r] * inv);
    if (sub == 0) {
      // zero-fill the 3 tile slots outside this row's 17-tile band
#pragma unroll
      for (int z = 0; z < 3; ++z) {
        const int slot = (toff + 17 + z) % 20;
        prow[slot * 16 + l15] = 0;
      }
    }
  }
}

// ---------------------------------------------------------------------------
// Kernel 5: context = P . V. Block = 64 queries x 512 features, 512 threads =
// 8 waves (qtile 0..3, fh 0..1). NO LDS STAGING, NO BARRIERS: V-fragments
// read directly from hbT (feature-major -> 4 lanes x 16B = 64B contiguous
// per feature row); band (327KB/block) is L2-resident with 5x cross-block
// overlap. 1-D grid + XCD swizzle for band L2 locality.
// ---------------------------------------------------------------------------
__global__ __launch_bounds__(512) void k_ctx(const u16* __restrict__ P,
                                             const u16* __restrict__ hbT,
                                             float* __restrict__ out) {
  const int t = threadIdx.x;
  const int wv = t >> 6, lane = t & 63;
  const int l15 = lane & 15, quad = lane >> 4;
  const int id  = blockIdx.x;                 // 0..511
  const int swz = (id & 7) * 64 + (id >> 3);  // bijective XCD swizzle
  const int fhalf = swz & 1;                  // paired halves stay on one XCD
  const int blk   = swz >> 1;                 // 0..255
  const int b  = blk >> 6;
  const int q0 = (blk & 63) * 64;
  const int qtile = wv & 3, fh = wv >> 2;
  const int qt0 = q0 + qtile * 16;

  // preload 10 P A-fragments (40 VGPR)
  const u16* prow = P + (size_t)(b * T_ + qt0 + l15) * WP2 + quad * 8;
  s16x8 aP[10];
#pragma unroll
  for (int c = 0; c < 10; ++c) aP[c] = *(const s16x8*)(prow + c * 32);

  const int tok0 = q0 - 256;

  for (int f8 = 0; f8 < 8; ++f8) {
    const int f0 = (fhalf * 8 + f8) * 64;
    const int g0 = f0 + (fh * 2 + 0) * 16 + l15;
    const int g1 = f0 + (fh * 2 + 1) * 16 + l15;
    const u16* vb0 = hbT + (size_t)(b * H_ + g0) * T_;
    const u16* vb1 = hbT + (size_t)(b * H_ + g1) * T_;
    f32x4 acc0 = (f32x4)0.0f, acc1 = (f32x4)0.0f;
    if (tok0 >= 0) {                     // fast path: imm-foldable offsets
      const u16* v0 = vb0 + tok0 + quad * 8;
      const u16* v1 = vb1 + tok0 + quad * 8;
#pragma unroll
      for (int c = 0; c < 10; ++c) {
        const s16x8 bv0 = *(const s16x8*)(v0 + c * 32);
        acc0 = __builtin_amdgcn_mfma_f32_16x16x32_bf16(aP[c], bv0, acc0, 0, 0, 0);
        const s16x8 bv1 = *(const s16x8*)(v1 + c * 32);
        acc1 = __builtin_amdgcn_mfma_f32_16x16x32_bf16(aP[c], bv1, acc1, 0, 0, 0);
      }
    } else {                             // first 4 q-blocks/batch: clamp toks
#pragma unroll
      for (int c = 0; c < 10; ++c) {
        int tok = tok0 + c * 32 + quad * 8;
        if (tok < 0) tok = 0;            // P is zero there
        const s16x8 bv0 = *(const s16x8*)(vb0 + tok);
        acc0 = __builtin_amdgcn_mfma_f32_16x16x32_bf16(aP[c], bv0, acc0, 0, 0, 0);
        const s16x8 bv1 = *(const s16x8*)(vb1 + tok);
        acc1 = __builtin_amdgcn_mfma_f32_16x16x32_bf16(aP[c], bv1, acc1, 0, 0, 0);
      }
    }
#pragma unroll
    for (int r = 0; r < 4; ++r) {
      const size_t orow = (size_t)(b * T_ + qt0 + quad * 4 + r) * H_ + f0;
      out[orow + (fh * 2 + 0) * 16 + l15] = acc0[r];
      out[orow + (fh * 2 + 1) * 16 + l15] = acc1[r];
    }
  }
}

// ---------------------------------------------------------------------------
extern "C" void kernel_launch(void* const* d_in, const int* in_sizes, int n_in,
                              void* d_out, int out_size, void* d_ws, size_t ws_size,
                              hipStream_t stream) {
  const float* h  = (const float*)d_in[0];
  const float* Wf = (const float*)d_in[1];

  char* ws = (char*)d_ws;
  // layout: hb 32M | hbT 32M | Kb 32M | Wb 2M | P 10.5M
  u16* hb  = (u16*)(ws);
  u16* hbT = (u16*)(ws + (size_t)33554432);
  u16* Kb  = (u16*)(ws + (size_t)67108864);
  u16* Wb  = (u16*)(ws + (size_t)100663296);
  u16* P   = (u16*)(ws + (size_t)102760448);   // 16384*320*2 = 10,485,760 B
  float* out = (float*)d_out;

  k_convT <<<dim3(H_ / 64, T_ / 64, B_), 256, 0, stream>>>(h, hb, hbT);
  k_convW <<<dim3(512), 256, 0, stream>>>(Wf, Wb);
  k_gemmK <<<dim3(H_ / 128, (B_ * T_) / 128), 256, 0, stream>>>(hb, Wb, Kb);
  k_scores<<<dim3((B_ * T_) / 32), 512, 0, stream>>>(hb, Kb, P);
  k_ctx   <<<dim3(2 * (B_ * T_) / 64), 512, 0, stream>>>(P, hbT, out);
}

// Round 2
// 329.202 us; speedup vs baseline: 1.0007x; 1.0007x over previous
//
#include <hip/hip_runtime.h>
#include <hip/hip_bf16.h>

// Problem constants (setup_inputs is fixed: B=4, T=4096, H=1024, T_hist=256)
#define B_ 4
#define T_ 4096
#define H_ 1024
#define WP2 320  // P width: col j <-> token (q&~63) - 256 + j

typedef short  s16x8 __attribute__((ext_vector_type(8)));
typedef float  f32x4 __attribute__((ext_vector_type(4)));
typedef unsigned short u16;

static __device__ __forceinline__ u16 bf16rn(float f) {
  unsigned int u = __float_as_uint(f);
  u += 0x7fffu + ((u >> 16) & 1u);
  return (u16)(u >> 16);
}

// async 16B global -> LDS (direct-to-shared DMA; LDS dest = wave base + lane*16)
static __device__ __forceinline__ void gl2lds16(const u16* g, u16* l) {
  __builtin_amdgcn_global_load_lds(
      (__attribute__((address_space(1))) void*)(g),
      (__attribute__((address_space(3))) void*)(l), 16, 0, 0);
}

// ---------------------------------------------------------------------------
// Kernel 1: h (fp32) -> hb (bf16 row-major) + hbT (bf16, per-batch [H][T])
// ---------------------------------------------------------------------------
__global__ __launch_bounds__(256) void k_convT(const float* __restrict__ h,
                                               u16* __restrict__ hb,
                                               u16* __restrict__ hbT) {
  __shared__ u16 tile[64][72];
  const int b  = blockIdx.z;
  const int t0 = blockIdx.y * 64;
  const int c0 = blockIdx.x * 64;
  const int t  = threadIdx.x;
  {
    const int r  = t >> 2;
    const int cq = (t & 3) << 4;
    const size_t g = (size_t)(b * T_ + t0 + r) * H_ + c0 + cq;
    const f32x4* src = (const f32x4*)(h + g);
    u16 o[16];
#pragma unroll
    for (int v = 0; v < 4; ++v) {
      f32x4 x = src[v];
#pragma unroll
      for (int j = 0; j < 4; ++j) o[v * 4 + j] = bf16rn(x[j]);
    }
    s16x8 w0, w1;
#pragma unroll
    for (int j = 0; j < 8; ++j) { w0[j] = (short)o[j]; w1[j] = (short)o[8 + j]; }
    *(s16x8*)(hb + g)     = w0;
    *(s16x8*)(hb + g + 8) = w1;
    *(s16x8*)&tile[r][cq]     = w0;
    *(s16x8*)&tile[r][cq + 8] = w1;
  }
  __syncthreads();
  {
    const int c  = t >> 2;
    const int ch = t & 3;
#pragma unroll
    for (int p = 0; p < 2; ++p) {
      const int k0 = (ch + p * 4) * 8;
      s16x8 w;
#pragma unroll
      for (int j = 0; j < 8; ++j) w[j] = (short)tile[k0 + j][c];
      *(s16x8*)(hbT + (size_t)(b * H_ + c0 + c) * T_ + t0 + k0) = w;
    }
  }
}

// ---------------------------------------------------------------------------
// Kernel 2: W (fp32) -> Wb (bf16)
// ---------------------------------------------------------------------------
__global__ __launch_bounds__(256) void k_convW(const float* __restrict__ src,
                                               u16* __restrict__ dst) {
  const int i = (blockIdx.x * 256 + threadIdx.x) * 8;
  f32x4 a = *(const f32x4*)(src + i);
  f32x4 b = *(const f32x4*)(src + i + 4);
  s16x8 w;
#pragma unroll
  for (int j = 0; j < 4; ++j) {
    w[j]     = (short)bf16rn(a[j]);
    w[4 + j] = (short)bf16rn(b[j]);
  }
  *(s16x8*)(dst + i) = w;
}

// ---------------------------------------------------------------------------
// Kernel 3: Kb = hb . Wb^T  (M=16384, N=1024, K=1024), m97-style:
// fragment-linear LDS (chunk id = row*4 + quad, 16B each) + global_load_lds.
// XCD-aware bijective swizzle (m204): nwg=1024, each XCD owns 16 contiguous
// row-panels x all 8 col-tiles -> A-panel fetched once per XCD, not 8x.
// ---------------------------------------------------------------------------
__global__ __launch_bounds__(256) void k_gemmK(const u16* __restrict__ hb,
                                               const u16* __restrict__ Wb,
                                               u16* __restrict__ Kb) {
  __shared__ __align__(16) u16 As[512 * 8];   // 128 rows x 4 chunks of 16B
  __shared__ __align__(16) u16 Bs[512 * 8];
  const int t = threadIdx.x;
  const int id  = blockIdx.y * gridDim.x + blockIdx.x;  // 0..1023, x fastest
  const int swz = (id & 7) * 128 + (id >> 3);           // bijective (1024%8==0)
  const int row0 = (swz >> 3) * 128;
  const int col0 = (swz & 7) * 128;
  const int lane = t & 63, wv = t >> 6;
  const int wr = wv >> 1, wc = wv & 1;
  const int l15 = lane & 15, quad = lane >> 4;

  const int c0 = t, c1 = t + 256;
  const size_t gA0 = (size_t)(row0 + (c0 >> 2)) * H_ + (c0 & 3) * 8;
  const size_t gA1 = (size_t)(row0 + (c1 >> 2)) * H_ + (c1 & 3) * 8;
  const size_t gB0 = (size_t)(col0 + (c0 >> 2)) * H_ + (c0 & 3) * 8;
  const size_t gB1 = (size_t)(col0 + (c1 >> 2)) * H_ + (c1 & 3) * 8;

  f32x4 acc[4][4];
#pragma unroll
  for (int m = 0; m < 4; ++m)
#pragma unroll
    for (int n = 0; n < 4; ++n) acc[m][n] = (f32x4)0.0f;

  for (int k0 = 0; k0 < H_; k0 += 32) {
    __syncthreads();
    gl2lds16(hb + gA0 + k0, &As[c0 * 8]);
    gl2lds16(hb + gA1 + k0, &As[c1 * 8]);
    gl2lds16(Wb + gB0 + k0, &Bs[c0 * 8]);
    gl2lds16(Wb + gB1 + k0, &Bs[c1 * 8]);
    __syncthreads();
    s16x8 aF[4], bF[4];
#pragma unroll
    for (int mt = 0; mt < 4; ++mt)
      aF[mt] = *(const s16x8*)&As[((wr * 64 + mt * 16 + l15) * 4 + quad) * 8];
#pragma unroll
    for (int nt = 0; nt < 4; ++nt)
      bF[nt] = *(const s16x8*)&Bs[((wc * 64 + nt * 16 + l15) * 4 + quad) * 8];
#pragma unroll
    for (int mt = 0; mt < 4; ++mt)
#pragma unroll
      for (int nt = 0; nt < 4; ++nt)
        acc[mt][nt] = __builtin_amdgcn_mfma_f32_16x16x32_bf16(aF[mt], bF[nt],
                                                              acc[mt][nt], 0, 0, 0);
  }
#pragma unroll
  for (int mt = 0; mt < 4; ++mt)
#pragma unroll
    for (int nt = 0; nt < 4; ++nt)
#pragma unroll
      for (int r = 0; r < 4; ++r) {
        const int row = row0 + wr * 64 + mt * 16 + quad * 4 + r;
        const int col = col0 + wc * 64 + nt * 16 + l15;
        Kb[(size_t)row * H_ + col] = bf16rn(acc[mt][nt][r]);
      }
}

// ---------------------------------------------------------------------------
// Kernel 4: banded scores + softmax -> P. Direct-from-L2 K reads (no LDS),
// but now with EXPLICIT MLP: __launch_bounds__(512,4) gives the regalloc a
// 128-VGPR budget (round-1's bare bound capped at ~64 and demoted operands
// to serial re-loads -> latency-bound, MfmaUtil 4.8%). Flattened 32-step
// K-loop with a 2-deep named A/B register pipeline: ~6 loads (6KB) in
// flight per wave, 16 waves/CU -> L2 latency fully covered.
// ---------------------------------------------------------------------------
__global__ __launch_bounds__(512, 4) void k_scores(const u16* __restrict__ hb,
                                                   const u16* __restrict__ Kb,
                                                   u16* __restrict__ P) {
  __shared__ float Sred[2][4][16];
  const int t = threadIdx.x;
  const int wv = t >> 6, lane = t & 63;
  const int l15 = lane & 15, quad = lane >> 4;
  const int id  = blockIdx.x;                 // 0..511
  const int swz = (id & 7) * 64 + (id >> 3);  // bijective XCD swizzle
  const int b  = swz >> 7;
  const int q0 = (swz & 127) * 32;
  const int qt = wv & 1;
  const int sub = wv >> 1;
  const int qt0 = q0 + qt * 16;
  const int ktbase = (sub == 0) ? 0 : (1 + sub * 4);   // 0,5,9,13
  const int nkt = (sub == 0) ? 5 : 4;

  const u16* qbase = hb + (size_t)(b * T_ + qt0 + l15) * H_ + quad * 8;

  // per-tile K base pointers; token = q0-256 + (qt+ktbase+i)*16 + l15
  const u16* kbas[5];
#pragma unroll
  for (int i = 0; i < 5; ++i) {
    int tok = q0 - 256 + (qt + ktbase + i) * 16 + l15;
    if (tok < 0) tok = 0;                // garbage rows, masked below
    kbas[i] = Kb + (size_t)(b * T_ + tok) * H_ + quad * 8;
  }

  f32x4 acc[5];
#pragma unroll
  for (int i = 0; i < 5; ++i) acc[i] = (f32x4)0.0f;

  // 2-deep software pipeline over 32 K=32 steps (offset = s*32 bf16)
  s16x8 qA = *(const s16x8*)(qbase);
  s16x8 kA[5], kB[5];
#pragma unroll
  for (int i = 0; i < 5; ++i)
    if (i < nkt) kA[i] = *(const s16x8*)(kbas[i]);

#pragma unroll
  for (int s = 0; s < 32; s += 2) {
    const s16x8 qB = *(const s16x8*)(qbase + (s + 1) * 32);
#pragma unroll
    for (int i = 0; i < 5; ++i)
      if (i < nkt) kB[i] = *(const s16x8*)(kbas[i] + (s + 1) * 32);
#pragma unroll
    for (int i = 0; i < 5; ++i)
      if (i < nkt) acc[i] = __builtin_amdgcn_mfma_f32_16x16x32_bf16(qA, kA[i], acc[i], 0, 0, 0);
    if (s + 2 < 32) {
      qA = *(const s16x8*)(qbase + (s + 2) * 32);
#pragma unroll
      for (int i = 0; i < 5; ++i)
        if (i < nkt) kA[i] = *(const s16x8*)(kbas[i] + (s + 2) * 32);
    }
#pragma unroll
    for (int i = 0; i < 5; ++i)
      if (i < nkt) acc[i] = __builtin_amdgcn_mfma_f32_16x16x32_bf16(qB, kB[i], acc[i], 0, 0, 0);
  }

  const float scale = 0.03125f;  // 1/sqrt(1024); |scores|<~6 so raw exp is safe
#pragma unroll
  for (int r = 0; r < 4; ++r) {
    const int q = qt0 + quad * 4 + r;
    float sum = 0.0f;
#pragma unroll
    for (int i = 0; i < 5; ++i) {
      if (i < nkt) {
        const int k = qt0 - 256 + (ktbase + i) * 16 + l15;
        const bool valid = (k >= 0) && (k <= q) && (k >= q - 255);
        const float p = valid ? __expf(acc[i][r] * scale) : 0.0f;
        acc[i][r] = p;
        sum += p;
      }
    }
    sum += __shfl_xor(sum, 1);
    sum += __shfl_xor(sum, 2);
    sum += __shfl_xor(sum, 4);
    sum += __shfl_xor(sum, 8);
    if (l15 == 0) Sred[qt][sub][quad * 4 + r] = sum;
  }
  __syncthreads();
  const int toff = ((q0 & 32) >> 4) + qt;  // q-tile slot within 64-block: 0..3
#pragma unroll
  for (int r = 0; r < 4; ++r) {
    const int q = qt0 + quad * 4 + r;
    const int row = quad * 4 + r;
    const float inv = 1.0f / (Sred[qt][0][row] + Sred[qt][1][row] +
                              Sred[qt][2][row] + Sred[qt][3][row]);
    u16* prow = P + (size_t)(b * T_ + q) * WP2;
#pragma unroll
    for (int i = 0; i < 5; ++i)
      if (i < nkt) prow[(toff + ktbase + i) * 16 + l15] = bf16rn(acc[i][r] * inv);
    if (sub == 0) {
      // zero-fill the 3 tile slots outside this row's 17-tile band
#pragma unroll
      for (int z = 0; z < 3; ++z) {
        const int slot = (toff + 17 + z) % 20;
        prow[slot * 16 + l15] = 0;
      }
    }
  }
}

// ---------------------------------------------------------------------------
// Kernel 5: context = P . V, direct-from-L2 V reads (no LDS, no barriers).
// __launch_bounds__(512,4): 128-VGPR budget so aP[10] (40 VGPR) stays
// RESIDENT (round-1 compiler demoted it to re-loads at 44 VGPR total).
// Clamped token offsets precomputed once (uniform code, no edge branch);
// 2-deep named A/B pipeline keeps ~4KB/wave of V loads in flight.
// ---------------------------------------------------------------------------
__global__ __launch_bounds__(512, 4) void k_ctx(const u16* __restrict__ P,
                                                const u16* __restrict__ hbT,
                                                float* __restrict__ out) {
  const int t = threadIdx.x;
  const int wv = t >> 6, lane = t & 63;
  const int l15 = lane & 15, quad = lane >> 4;
  const int id  = blockIdx.x;                 // 0..511
  const int swz = (id & 7) * 64 + (id >> 3);  // bijective XCD swizzle
  const int fhalf = swz & 1;                  // paired halves stay on one XCD
  const int blk   = swz >> 1;                 // 0..255
  const int b  = blk >> 6;
  const int q0 = (blk & 63) * 64;
  const int qtile = wv & 3, fh = wv >> 2;
  const int qt0 = q0 + qtile * 16;

  // preload 10 P A-fragments (40 VGPR, resident under the 128-VGPR budget)
  const u16* prow = P + (size_t)(b * T_ + qt0 + l15) * WP2 + quad * 8;
  s16x8 aP[10];
#pragma unroll
  for (int c = 0; c < 10; ++c) aP[c] = *(const s16x8*)(prow + c * 32);

  // clamped per-lane token offsets (P is zero on clamped rows -> contributes 0)
  const int tok0 = q0 - 256;
  int off[10];
#pragma unroll
  for (int c = 0; c < 10; ++c) {
    int tk = tok0 + c * 32 + quad * 8;
    off[c] = tk < 0 ? 0 : tk;
  }

  for (int f8 = 0; f8 < 8; ++f8) {
    const int f0 = (fhalf * 8 + f8) * 64;
    const int g0 = f0 + (fh * 2 + 0) * 16 + l15;
    const int g1 = f0 + (fh * 2 + 1) * 16 + l15;
    const u16* vb0 = hbT + (size_t)(b * H_ + g0) * T_;
    const u16* vb1 = hbT + (size_t)(b * H_ + g1) * T_;
    f32x4 acc0 = (f32x4)0.0f, acc1 = (f32x4)0.0f;

    s16x8 b0A = *(const s16x8*)(vb0 + off[0]);
    s16x8 b1A = *(const s16x8*)(vb1 + off[0]);
#pragma unroll
    for (int c = 0; c < 10; c += 2) {
      const s16x8 b0B = *(const s16x8*)(vb0 + off[c + 1]);
      const s16x8 b1B = *(const s16x8*)(vb1 + off[c + 1]);
      acc0 = __builtin_amdgcn_mfma_f32_16x16x32_bf16(aP[c], b0A, acc0, 0, 0, 0);
      acc1 = __builtin_amdgcn_mfma_f32_16x16x32_bf16(aP[c], b1A, acc1, 0, 0, 0);
      if (c + 2 < 10) {
        b0A = *(const s16x8*)(vb0 + off[c + 2]);
        b1A = *(const s16x8*)(vb1 + off[c + 2]);
      }
      acc0 = __builtin_amdgcn_mfma_f32_16x16x32_bf16(aP[c + 1], b0B, acc0, 0, 0, 0);
      acc1 = __builtin_amdgcn_mfma_f32_16x16x32_bf16(aP[c + 1], b1B, acc1, 0, 0, 0);
    }
#pragma unroll
    for (int r = 0; r < 4; ++r) {
      const size_t orow = (size_t)(b * T_ + qt0 + quad * 4 + r) * H_ + f0;
      out[orow + (fh * 2 + 0) * 16 + l15] = acc0[r];
      out[orow + (fh * 2 + 1) * 16 + l15] = acc1[r];
    }
  }
}

// ---------------------------------------------------------------------------
extern "C" void kernel_launch(void* const* d_in, const int* in_sizes, int n_in,
                              void* d_out, int out_size, void* d_ws, size_t ws_size,
                              hipStream_t stream) {
  const float* h  = (const float*)d_in[0];
  const float* Wf = (const float*)d_in[1];

  char* ws = (char*)d_ws;
  // layout: hb 32M | hbT 32M | Kb 32M | Wb 2M | P 10.5M
  u16* hb  = (u16*)(ws);
  u16* hbT = (u16*)(ws + (size_t)33554432);
  u16* Kb  = (u16*)(ws + (size_t)67108864);
  u16* Wb  = (u16*)(ws + (size_t)100663296);
  u16* P   = (u16*)(ws + (size_t)102760448);   // 16384*320*2 = 10,485,760 B
  float* out = (float*)d_out;

  k_convT <<<dim3(H_ / 64, T_ / 64, B_), 256, 0, stream>>>(h, hb, hbT);
  k_convW <<<dim3(512), 256, 0, stream>>>(Wf, Wb);
  k_gemmK <<<dim3(H_ / 128, (B_ * T_) / 128), 256, 0, stream>>>(hb, Wb, Kb);
  k_scores<<<dim3((B_ * T_) / 32), 512, 0, stream>>>(hb, Kb, P);
  k_ctx   <<<dim3(2 * (B_ * T_) / 64), 512, 0, stream>>>(P, hbT, out);
}

// Round 3
// 231.513 us; speedup vs baseline: 1.4229x; 1.4220x over previous
//
#include <hip/hip_runtime.h>
#include <hip/hip_bf16.h>

// Problem constants (setup_inputs is fixed: B=4, T=4096, H=1024, T_hist=256)
#define B_ 4
#define T_ 4096
#define H_ 1024
#define WP2 320  // P width: col j <-> token (q&~63) - 256 + j

typedef short  s16x8 __attribute__((ext_vector_type(8)));
typedef float  f32x4 __attribute__((ext_vector_type(4)));
typedef unsigned short u16;

static __device__ __forceinline__ u16 bf16rn(float f) {
  unsigned int u = __float_as_uint(f);
  u += 0x7fffu + ((u >> 16) & 1u);
  return (u16)(u >> 16);
}

// async 16B global -> LDS (direct-to-shared DMA; LDS dest = wave base + lane*16)
static __device__ __forceinline__ void gl2lds16(const u16* g, u16* l) {
  __builtin_amdgcn_global_load_lds(
      (__attribute__((address_space(1))) void*)(g),
      (__attribute__((address_space(3))) void*)(l), 16, 0, 0);
}

// ---------------------------------------------------------------------------
// Kernel 1: h (fp32) -> hb (bf16 row-major) + hbT (bf16, per-batch [H][T])
// ---------------------------------------------------------------------------
__global__ __launch_bounds__(256) void k_convT(const float* __restrict__ h,
                                               u16* __restrict__ hb,
                                               u16* __restrict__ hbT) {
  __shared__ u16 tile[64][72];
  const int b  = blockIdx.z;
  const int t0 = blockIdx.y * 64;
  const int c0 = blockIdx.x * 64;
  const int t  = threadIdx.x;
  {
    const int r  = t >> 2;
    const int cq = (t & 3) << 4;
    const size_t g = (size_t)(b * T_ + t0 + r) * H_ + c0 + cq;
    const f32x4* src = (const f32x4*)(h + g);
    u16 o[16];
#pragma unroll
    for (int v = 0; v < 4; ++v) {
      f32x4 x = src[v];
#pragma unroll
      for (int j = 0; j < 4; ++j) o[v * 4 + j] = bf16rn(x[j]);
    }
    s16x8 w0, w1;
#pragma unroll
    for (int j = 0; j < 8; ++j) { w0[j] = (short)o[j]; w1[j] = (short)o[8 + j]; }
    *(s16x8*)(hb + g)     = w0;
    *(s16x8*)(hb + g + 8) = w1;
    *(s16x8*)&tile[r][cq]     = w0;
    *(s16x8*)&tile[r][cq + 8] = w1;
  }
  __syncthreads();
  {
    const int c  = t >> 2;
    const int ch = t & 3;
#pragma unroll
    for (int p = 0; p < 2; ++p) {
      const int k0 = (ch + p * 4) * 8;
      s16x8 w;
#pragma unroll
      for (int j = 0; j < 8; ++j) w[j] = (short)tile[k0 + j][c];
      *(s16x8*)(hbT + (size_t)(b * H_ + c0 + c) * T_ + t0 + k0) = w;
    }
  }
}

// ---------------------------------------------------------------------------
// Kernel 2: W (fp32) -> Wb (bf16)
// ---------------------------------------------------------------------------
__global__ __launch_bounds__(256) void k_convW(const float* __restrict__ src,
                                               u16* __restrict__ dst) {
  const int i = (blockIdx.x * 256 + threadIdx.x) * 8;
  f32x4 a = *(const f32x4*)(src + i);
  f32x4 b = *(const f32x4*)(src + i + 4);
  s16x8 w;
#pragma unroll
  for (int j = 0; j < 4; ++j) {
    w[j]     = (short)bf16rn(a[j]);
    w[4 + j] = (short)bf16rn(b[j]);
  }
  *(s16x8*)(dst + i) = w;
}

// ---------------------------------------------------------------------------
// Kernel 3: Kb = hb . Wb^T  (M=16384, N=1024, K=1024), m97-style:
// fragment-linear LDS + global_load_lds, XCD-bijective swizzle (round-1).
// ---------------------------------------------------------------------------
__global__ __launch_bounds__(256) void k_gemmK(const u16* __restrict__ hb,
                                               const u16* __restrict__ Wb,
                                               u16* __restrict__ Kb) {
  __shared__ __align__(16) u16 As[512 * 8];   // 128 rows x 4 chunks of 16B
  __shared__ __align__(16) u16 Bs[512 * 8];
  const int t = threadIdx.x;
  const int id  = blockIdx.y * gridDim.x + blockIdx.x;  // 0..1023, x fastest
  const int swz = (id & 7) * 128 + (id >> 3);           // bijective (1024%8==0)
  const int row0 = (swz >> 3) * 128;
  const int col0 = (swz & 7) * 128;
  const int lane = t & 63, wv = t >> 6;
  const int wr = wv >> 1, wc = wv & 1;
  const int l15 = lane & 15, quad = lane >> 4;

  const int c0 = t, c1 = t + 256;
  const size_t gA0 = (size_t)(row0 + (c0 >> 2)) * H_ + (c0 & 3) * 8;
  const size_t gA1 = (size_t)(row0 + (c1 >> 2)) * H_ + (c1 & 3) * 8;
  const size_t gB0 = (size_t)(col0 + (c0 >> 2)) * H_ + (c0 & 3) * 8;
  const size_t gB1 = (size_t)(col0 + (c1 >> 2)) * H_ + (c1 & 3) * 8;

  f32x4 acc[4][4];
#pragma unroll
  for (int m = 0; m < 4; ++m)
#pragma unroll
    for (int n = 0; n < 4; ++n) acc[m][n] = (f32x4)0.0f;

  for (int k0 = 0; k0 < H_; k0 += 32) {
    __syncthreads();
    gl2lds16(hb + gA0 + k0, &As[c0 * 8]);
    gl2lds16(hb + gA1 + k0, &As[c1 * 8]);
    gl2lds16(Wb + gB0 + k0, &Bs[c0 * 8]);
    gl2lds16(Wb + gB1 + k0, &Bs[c1 * 8]);
    __syncthreads();
    s16x8 aF[4], bF[4];
#pragma unroll
    for (int mt = 0; mt < 4; ++mt)
      aF[mt] = *(const s16x8*)&As[((wr * 64 + mt * 16 + l15) * 4 + quad) * 8];
#pragma unroll
    for (int nt = 0; nt < 4; ++nt)
      bF[nt] = *(const s16x8*)&Bs[((wc * 64 + nt * 16 + l15) * 4 + quad) * 8];
#pragma unroll
    for (int mt = 0; mt < 4; ++mt)
#pragma unroll
      for (int nt = 0; nt < 4; ++nt)
        acc[mt][nt] = __builtin_amdgcn_mfma_f32_16x16x32_bf16(aF[mt], bF[nt],
                                                              acc[mt][nt], 0, 0, 0);
  }
#pragma unroll
  for (int mt = 0; mt < 4; ++mt)
#pragma unroll
    for (int nt = 0; nt < 4; ++nt)
#pragma unroll
      for (int r = 0; r < 4; ++r) {
        const int row = row0 + wr * 64 + mt * 16 + quad * 4 + r;
        const int col = col0 + wc * 64 + nt * 16 + l15;
        Kb[(size_t)row * H_ + col] = bf16rn(acc[mt][nt][r]);
      }
}

// ---------------------------------------------------------------------------
// Kernel 4: banded scores + softmax -> P. STAGED (global_load_lds = block-wide
// MLP: rounds 1-2 proved scalar-load MLP is compiler-defeated), now DOUBLE-
// BUFFERED at 32-feature granularity: same total LDS as round-0 (36.9KB ->
// 4 blocks/CU) but one barrier per phase and stage(next) overlaps compute(cur).
// 32 phases; per phase: stage 18KB into buf^1, 5 MFMA + 5 ds_read from buf.
// ---------------------------------------------------------------------------
__global__ __launch_bounds__(512) void k_scores(const u16* __restrict__ hb,
                                                const u16* __restrict__ Kb,
                                                u16* __restrict__ P) {
  __shared__ __align__(16) u16 Ks[2][1152 * 8];   // 2 x 18,432 B
  __shared__ float Sred[2][4][16];
  const int t = threadIdx.x;
  const int wv = t >> 6, lane = t & 63;
  const int l15 = lane & 15, quad = lane >> 4;
  const int id  = blockIdx.x;                 // 0..511
  const int swz = (id & 7) * 64 + (id >> 3);  // bijective XCD swizzle
  const int b  = swz >> 7;
  const int q0 = (swz & 127) * 32;
  const int qt = wv & 1;
  const int sub = wv >> 1;
  const int qt0 = q0 + qt * 16;
  const int ktbase = (sub == 0) ? 0 : (1 + sub * 4);   // 0,5,9,13
  const int nkt = (sub == 0) ? 5 : 4;

  const u16* qbase = hb + (size_t)(b * T_ + qt0 + l15) * H_ + quad * 8;

  // staging: 1152 chunks/slice (18 tok-tiles x 16 rows x 4 quads), 2 full
  // passes + 1 quarter pass (t<128, i.e. waves 0-1 -> wave-uniform).
  const u16* kst[3];
  int cid[3];
#pragma unroll
  for (int p = 0; p < 3; ++p) {
    int c = p * 512 + t;
    if (c > 1151) c = 1151;              // inactive lanes (never issued)
    cid[p] = c;
    const int m = c >> 6, lr = (c >> 2) & 15, qd = c & 3;
    int tok = q0 - 256 + m * 16 + lr;
    if (tok < 0) tok = 0;                // garbage rows, masked below
    kst[p] = Kb + (size_t)(b * T_ + tok) * H_ + qd * 8;
  }
  const bool p2 = (t < 128);

  f32x4 acc[5];
#pragma unroll
  for (int i = 0; i < 5; ++i) acc[i] = (f32x4)0.0f;

  // prologue: stage slice 0 into buf 0
  gl2lds16(kst[0], &Ks[0][cid[0] * 8]);
  gl2lds16(kst[1], &Ks[0][cid[1] * 8]);
  if (p2) gl2lds16(kst[2], &Ks[0][cid[2] * 8]);
  __syncthreads();

  int cur = 0;
  for (int s = 0; s < 32; ++s) {
    if (s + 1 < 32) {                    // stage next slice into other buffer
      const int off = (s + 1) * 32;
      gl2lds16(kst[0] + off, &Ks[cur ^ 1][cid[0] * 8]);
      gl2lds16(kst[1] + off, &Ks[cur ^ 1][cid[1] * 8]);
      if (p2) gl2lds16(kst[2] + off, &Ks[cur ^ 1][cid[2] * 8]);
    }
    const s16x8 aQ = *(const s16x8*)(qbase + s * 32);
#pragma unroll
    for (int i = 0; i < 5; ++i) {
      if (i < nkt) {                     // wave-uniform
        const int m = qt + ktbase + i;
        const s16x8 bK = *(const s16x8*)&Ks[cur][(m * 64 + l15 * 4 + quad) * 8];
        acc[i] = __builtin_amdgcn_mfma_f32_16x16x32_bf16(aQ, bK, acc[i], 0, 0, 0);
      }
    }
    __syncthreads();                     // drains next-stage; cur's reads done
    cur ^= 1;
  }

  const float scale = 0.03125f;  // 1/sqrt(1024); |scores|<~6 so raw exp is safe
#pragma unroll
  for (int r = 0; r < 4; ++r) {
    const int q = qt0 + quad * 4 + r;
    float sum = 0.0f;
#pragma unroll
    for (int i = 0; i < 5; ++i) {
      if (i < nkt) {
        const int k = qt0 - 256 + (ktbase + i) * 16 + l15;
        const bool valid = (k >= 0) && (k <= q) && (k >= q - 255);
        const float p = valid ? __expf(acc[i][r] * scale) : 0.0f;
        acc[i][r] = p;
        sum += p;
      }
    }
    sum += __shfl_xor(sum, 1);
    sum += __shfl_xor(sum, 2);
    sum += __shfl_xor(sum, 4);
    sum += __shfl_xor(sum, 8);
    if (l15 == 0) Sred[qt][sub][quad * 4 + r] = sum;
  }
  __syncthreads();
  const int toff = ((q0 & 32) >> 4) + qt;  // q-tile slot within 64-block: 0..3
#pragma unroll
  for (int r = 0; r < 4; ++r) {
    const int q = qt0 + quad * 4 + r;
    const int row = quad * 4 + r;
    const float inv = 1.0f / (Sred[qt][0][row] + Sred[qt][1][row] +
                              Sred[qt][2][row] + Sred[qt][3][row]);
    u16* prow = P + (size_t)(b * T_ + q) * WP2;
#pragma unroll
    for (int i = 0; i < 5; ++i)
      if (i < nkt) prow[(toff + ktbase + i) * 16 + l15] = bf16rn(acc[i][r] * inv);
    if (sub == 0) {
      // zero-fill the 3 tile slots outside this row's 17-tile band
#pragma unroll
      for (int z = 0; z < 3; ++z) {
        const int slot = (toff + 17 + z) % 20;
        prow[slot * 16 + l15] = 0;
      }
    }
  }
}

// ---------------------------------------------------------------------------
// Kernel 5: context = P . V. STAGED + double-buffered 32-feature V slices:
// 2 x 20,480B = 40,960B LDS (same as round-0 total). 16 phases; per phase:
// stage next slice (overlaps compute), 10 MFMA from current buffer, one
// barrier, then the 16-feature output column store (overlaps next staging).
// ---------------------------------------------------------------------------
__global__ __launch_bounds__(512) void k_ctx(const u16* __restrict__ P,
                                             const u16* __restrict__ hbT,
                                             float* __restrict__ out) {
  __shared__ __align__(16) u16 Vs[2][1280 * 8];   // 2 x 20,480 B
  const int t = threadIdx.x;
  const int wv = t >> 6, lane = t & 63;
  const int l15 = lane & 15, quad = lane >> 4;
  const int id  = blockIdx.x;                 // 0..511
  const int swz = (id & 7) * 64 + (id >> 3);  // bijective XCD swizzle
  const int fhalf = swz & 1;                  // paired halves stay on one XCD
  const int blk   = swz >> 1;                 // 0..255
  const int b  = blk >> 6;
  const int q0 = (blk & 63) * 64;
  const int qtile = wv & 3, fh = wv >> 2;
  const int qt0 = q0 + qtile * 16;

  // preload 10 P A-fragments (40 VGPR)
  const u16* prow = P + (size_t)(b * T_ + qt0 + l15) * WP2 + quad * 8;
  s16x8 aP[10];
#pragma unroll
  for (int c = 0; c < 10; ++c) aP[c] = *(const s16x8*)(prow + c * 32);

  // staging: 1280 chunks/slice (10 tok-grps x 2 feat-16 x 16 rows x 4 quads),
  // 2 full passes + 1 half pass (t<256 = waves 0-3, wave-uniform).
  const int tok0 = q0 - 256;
  const u16* vst[3];
  int cid[3];
#pragma unroll
  for (int p = 0; p < 3; ++p) {
    int c = p * 512 + t;
    if (c > 1279) c = 1279;              // inactive lanes (never issued)
    cid[p] = c;
    const int cg = c >> 7, ft = (c >> 6) & 1, lr = (c >> 2) & 15, qd = c & 3;
    const int fr = ft * 16 + lr;
    int tok = tok0 + (cg * 4 + qd) * 8;
    if (tok < 0) tok = 0;                // P is zero there
    vst[p] = hbT + (size_t)(b * H_ + fr) * T_ + tok;
  }
  const bool p2 = (t < 256);
  const size_t fbase = (size_t)(fhalf * 512) * T_;  // feature offset of half
  const size_t fstep = (size_t)32 * T_;             // per 32-feature slice

  // prologue: stage slice 0 into buf 0
  gl2lds16(vst[0] + fbase, &Vs[0][cid[0] * 8]);
  gl2lds16(vst[1] + fbase, &Vs[0][cid[1] * 8]);
  if (p2) gl2lds16(vst[2] + fbase, &Vs[0][cid[2] * 8]);
  __syncthreads();

  int cur = 0;
  for (int g = 0; g < 16; ++g) {
    if (g + 1 < 16) {                    // stage next slice into other buffer
      const size_t off = fbase + (size_t)(g + 1) * fstep;
      gl2lds16(vst[0] + off, &Vs[cur ^ 1][cid[0] * 8]);
      gl2lds16(vst[1] + off, &Vs[cur ^ 1][cid[1] * 8]);
      if (p2) gl2lds16(vst[2] + off, &Vs[cur ^ 1][cid[2] * 8]);
    }
    f32x4 acc = (f32x4)0.0f;
#pragma unroll
    for (int c = 0; c < 10; ++c) {
      const s16x8 bv =
          *(const s16x8*)&Vs[cur][(c * 128 + fh * 64 + l15 * 4 + quad) * 8];
      acc = __builtin_amdgcn_mfma_f32_16x16x32_bf16(aP[c], bv, acc, 0, 0, 0);
    }
    __syncthreads();                     // drains next-stage; cur's reads done
    // store after the barrier: overlaps the next phase's staging latency
    const int f0 = (fhalf * 16 + g) * 32 + fh * 16 + l15;
#pragma unroll
    for (int r = 0; r < 4; ++r)
      out[(size_t)(b * T_ + qt0 + quad * 4 + r) * H_ + f0] = acc[r];
    cur ^= 1;
  }
}

// ---------------------------------------------------------------------------
extern "C" void kernel_launch(void* const* d_in, const int* in_sizes, int n_in,
                              void* d_out, int out_size, void* d_ws, size_t ws_size,
                              hipStream_t stream) {
  const float* h  = (const float*)d_in[0];
  const float* Wf = (const float*)d_in[1];

  char* ws = (char*)d_ws;
  // layout: hb 32M | hbT 32M | Kb 32M | Wb 2M | P 10.5M
  u16* hb  = (u16*)(ws);
  u16* hbT = (u16*)(ws + (size_t)33554432);
  u16* Kb  = (u16*)(ws + (size_t)67108864);
  u16* Wb  = (u16*)(ws + (size_t)100663296);
  u16* P   = (u16*)(ws + (size_t)102760448);   // 16384*320*2 = 10,485,760 B
  float* out = (float*)d_out;

  k_convT <<<dim3(H_ / 64, T_ / 64, B_), 256, 0, stream>>>(h, hb, hbT);
  k_convW <<<dim3(512), 256, 0, stream>>>(Wf, Wb);
  k_gemmK <<<dim3(H_ / 128, (B_ * T_) / 128), 256, 0, stream>>>(hb, Wb, Kb);
  k_scores<<<dim3((B_ * T_) / 32), 512, 0, stream>>>(hb, Kb, P);
  k_ctx   <<<dim3(2 * (B_ * T_) / 64), 512, 0, stream>>>(P, hbT, out);
}